// Round 1
// baseline (304.000 us; speedup 1.0000x reference)
//
#include <hip/hip_runtime.h>
#include <math.h>

#define NEG_SLOPE 0.2f
#define LN_EPS 1e-5f

// ---------------- CSR build (group edges by dst) ----------------
__global__ void hist_kernel(const int* __restrict__ ei, int E, int N, int* __restrict__ cnt) {
  int e = blockIdx.x * blockDim.x + threadIdx.x;
  if (e >= E + N) return;
  int dst = (e < E) ? ei[E + e] : (e - E);   // self-loops appended
  atomicAdd(&cnt[dst], 1);
}

__global__ void scan_kernel(const int* __restrict__ cnt, int* __restrict__ offs, int n) {
  __shared__ int buf[1024];
  __shared__ int carry_s;
  int tid = threadIdx.x;
  if (tid == 0) carry_s = 0;
  __syncthreads();
  int nchunks = (n + 1023) >> 10;
  for (int ch = 0; ch < nchunks; ++ch) {
    int idx = (ch << 10) + tid;
    int v = (idx < n) ? cnt[idx] : 0;
    buf[tid] = v;
    __syncthreads();
    for (int ofs = 1; ofs < 1024; ofs <<= 1) {
      int t = (tid >= ofs) ? buf[tid - ofs] : 0;
      __syncthreads();
      if (tid >= ofs) buf[tid] += t;
      __syncthreads();
    }
    int incl = buf[tid];
    int carry = carry_s;
    if (idx < n) offs[idx] = carry + incl - v;  // exclusive scan
    __syncthreads();
    if (tid == 1023) carry_s = carry + incl;
    __syncthreads();
  }
  if (tid == 0) offs[n] = carry_s;
}

__global__ void scatter_kernel(const int* __restrict__ ei, int E, int N,
                               const int* __restrict__ offs, int* __restrict__ cursor,
                               int* __restrict__ esrc) {
  int e = blockIdx.x * blockDim.x + threadIdx.x;
  if (e >= E + N) return;
  int src, dst;
  if (e < E) { src = ei[e]; dst = ei[E + e]; }
  else       { src = e - E; dst = src; }
  int pos = atomicAdd(&cursor[dst], 1);
  esrc[offs[dst] + pos] = src;
}

// ---------------- layer-1 linear: x[N,8] @ W[8,256] (+bias), both lin_l and lin_r ----------------
__global__ __launch_bounds__(256) void gemm1_kernel(
    const float* __restrict__ x,
    const float* __restrict__ Wl, const float* __restrict__ bl,
    const float* __restrict__ Wr, const float* __restrict__ br,
    float* __restrict__ xl1, float* __restrict__ xr1, int N) {
  int tid = threadIdx.x;
  float wl[8], wr[8];
#pragma unroll
  for (int k = 0; k < 8; ++k) { wl[k] = Wl[k * 256 + tid]; wr[k] = Wr[k * 256 + tid]; }
  float blv = bl[tid], brv = br[tid];
  for (int n = blockIdx.x; n < N; n += gridDim.x) {
    float4 xa = ((const float4*)x)[n * 2];
    float4 xb = ((const float4*)x)[n * 2 + 1];
    float xs[8] = {xa.x, xa.y, xa.z, xa.w, xb.x, xb.y, xb.z, xb.w};
    float al = blv, ar = brv;
#pragma unroll
    for (int k = 0; k < 8; ++k) { al = fmaf(xs[k], wl[k], al); ar = fmaf(xs[k], wr[k], ar); }
    xl1[n * 256 + tid] = al;
    xr1[n * 256 + tid] = ar;
  }
}

// ---------------- layer-2 linear: h1[N,64] @ W[64,128] (+bias) ----------------
__global__ __launch_bounds__(128) void gemm2_kernel(
    const float* __restrict__ h1,
    const float* __restrict__ Wl, const float* __restrict__ bl,
    const float* __restrict__ Wr, const float* __restrict__ br,
    float* __restrict__ xl2, float* __restrict__ xr2, int N) {
  int tid = threadIdx.x;
  float blv = bl[tid], brv = br[tid];
  int ngrp = (N + 3) >> 2;
  for (int grp = blockIdx.x; grp < ngrp; grp += gridDim.x) {
    int n0 = grp << 2;
    int nn = (N - n0 < 4) ? (N - n0) : 4;
    if (nn == 4) {
      float al0 = blv, al1 = blv, al2 = blv, al3 = blv;
      float ar0 = brv, ar1 = brv, ar2 = brv, ar3 = brv;
      const float* hp = h1 + (size_t)n0 * 64;
      for (int k = 0; k < 64; ++k) {
        float wlv = Wl[k * 128 + tid];
        float wrv = Wr[k * 128 + tid];
        float h0 = hp[k], h1v = hp[64 + k], h2v = hp[128 + k], h3 = hp[192 + k];
        al0 = fmaf(h0, wlv, al0); ar0 = fmaf(h0, wrv, ar0);
        al1 = fmaf(h1v, wlv, al1); ar1 = fmaf(h1v, wrv, ar1);
        al2 = fmaf(h2v, wlv, al2); ar2 = fmaf(h2v, wrv, ar2);
        al3 = fmaf(h3, wlv, al3); ar3 = fmaf(h3, wrv, ar3);
      }
      xl2[(size_t)(n0 + 0) * 128 + tid] = al0; xr2[(size_t)(n0 + 0) * 128 + tid] = ar0;
      xl2[(size_t)(n0 + 1) * 128 + tid] = al1; xr2[(size_t)(n0 + 1) * 128 + tid] = ar1;
      xl2[(size_t)(n0 + 2) * 128 + tid] = al2; xr2[(size_t)(n0 + 2) * 128 + tid] = ar2;
      xl2[(size_t)(n0 + 3) * 128 + tid] = al3; xr2[(size_t)(n0 + 3) * 128 + tid] = ar3;
    } else {
      for (int j = 0; j < nn; ++j) {
        int n = n0 + j;
        float al = blv, ar = brv;
        const float* hp = h1 + (size_t)n * 64;
        for (int k = 0; k < 64; ++k) {
          float hv = hp[k];
          al = fmaf(hv, Wl[k * 128 + tid], al);
          ar = fmaf(hv, Wr[k * 128 + tid], ar);
        }
        xl2[(size_t)n * 128 + tid] = al;
        xr2[(size_t)n * 128 + tid] = ar;
      }
    }
  }
}

// ---------------- fused GATv2 attention + head-mean + bias + LN + ReLU, layer 1 ----------------
// one wave per dst node; lane = h*16 + cq; lane's float4 of row n is at flat offset n*256 + 4*lane
__global__ __launch_bounds__(256) void attn1_kernel(
    const float* __restrict__ xl1, const float* __restrict__ xr1,
    const float* __restrict__ att, const float* __restrict__ b1,
    const float* __restrict__ g, const float* __restrict__ be,
    const int* __restrict__ offs, const int* __restrict__ esrc,
    float* __restrict__ h1, int N) {
  int lane = threadIdx.x & 63;
  int wid = blockIdx.x * (blockDim.x >> 6) + (threadIdx.x >> 6);
  int wstride = gridDim.x * (blockDim.x >> 6);
  int cq = lane & 15;
  float4 attq = ((const float4*)att)[lane];
  float4 b1q = ((const float4*)b1)[cq];
  float4 gq = ((const float4*)g)[cq];
  float4 beq = ((const float4*)be)[cq];
  for (int i = wid; i < N; i += wstride) {
    float4 xrq = ((const float4*)xr1)[i * 64 + lane];
    float4 acc = make_float4(0.f, 0.f, 0.f, 0.f);
    float m = -INFINITY, den = 0.f;
    int beg = offs[i], end = offs[i + 1];
    for (int p = beg; p < end; ++p) {
      int s = esrc[p];
      float4 xl = ((const float4*)xl1)[s * 64 + lane];
      float t0 = xl.x + xrq.x; t0 = t0 > 0.f ? t0 : NEG_SLOPE * t0;
      float t1 = xl.y + xrq.y; t1 = t1 > 0.f ? t1 : NEG_SLOPE * t1;
      float t2 = xl.z + xrq.z; t2 = t2 > 0.f ? t2 : NEG_SLOPE * t2;
      float t3 = xl.w + xrq.w; t3 = t3 > 0.f ? t3 : NEG_SLOPE * t3;
      float sc = attq.x * t0;
      sc = fmaf(attq.y, t1, sc);
      sc = fmaf(attq.z, t2, sc);
      sc = fmaf(attq.w, t3, sc);
#pragma unroll
      for (int msk = 8; msk >= 1; msk >>= 1) sc += __shfl_xor(sc, msk, 64);
      // online softmax (branchless; exp(-inf)=0 handles first edge)
      float mn = fmaxf(m, sc);
      float corr = __expf(m - mn);
      float w = __expf(sc - mn);
      den = fmaf(den, corr, w);
      acc.x = fmaf(acc.x, corr, w * xl.x);
      acc.y = fmaf(acc.y, corr, w * xl.y);
      acc.z = fmaf(acc.z, corr, w * xl.z);
      acc.w = fmaf(acc.w, corr, w * xl.w);
      m = mn;
    }
    float inv = 1.0f / den;
    float v0 = acc.x * inv, v1 = acc.y * inv, v2 = acc.z * inv, v3 = acc.w * inv;
    // mean over 4 heads (lanes differing in bits 4,5)
    v0 += __shfl_xor(v0, 16, 64); v0 += __shfl_xor(v0, 32, 64);
    v1 += __shfl_xor(v1, 16, 64); v1 += __shfl_xor(v1, 32, 64);
    v2 += __shfl_xor(v2, 16, 64); v2 += __shfl_xor(v2, 32, 64);
    v3 += __shfl_xor(v3, 16, 64); v3 += __shfl_xor(v3, 32, 64);
    v0 = 0.25f * v0 + b1q.x;
    v1 = 0.25f * v1 + b1q.y;
    v2 = 0.25f * v2 + b1q.z;
    v3 = 0.25f * v3 + b1q.w;
    // LayerNorm over 64 channels (16 lanes x 4 each; all head-groups hold identical copies)
    float s1 = v0 + v1 + v2 + v3;
#pragma unroll
    for (int msk = 8; msk >= 1; msk >>= 1) s1 += __shfl_xor(s1, msk, 64);
    float mu = s1 * (1.0f / 64.0f);
    float d0 = v0 - mu, d1 = v1 - mu, d2 = v2 - mu, d3 = v3 - mu;
    float s2 = d0 * d0 + d1 * d1 + d2 * d2 + d3 * d3;
#pragma unroll
    for (int msk = 8; msk >= 1; msk >>= 1) s2 += __shfl_xor(s2, msk, 64);
    float rstd = rsqrtf(s2 * (1.0f / 64.0f) + LN_EPS);
    float y0 = fmaxf(fmaf(d0 * rstd, gq.x, beq.x), 0.f);
    float y1 = fmaxf(fmaf(d1 * rstd, gq.y, beq.y), 0.f);
    float y2 = fmaxf(fmaf(d2 * rstd, gq.z, beq.z), 0.f);
    float y3 = fmaxf(fmaf(d3 * rstd, gq.w, beq.w), 0.f);
    if (lane < 16) ((float4*)h1)[i * 16 + cq] = make_float4(y0, y1, y2, y3);
  }
}

// ---------------- layer 2: same structure, 32 channels/head -> float2 per lane ----------------
__global__ __launch_bounds__(256) void attn2_kernel(
    const float* __restrict__ xl2, const float* __restrict__ xr2,
    const float* __restrict__ att, const float* __restrict__ b2,
    const float* __restrict__ g, const float* __restrict__ be,
    const int* __restrict__ offs, const int* __restrict__ esrc,
    float* __restrict__ h2, int N) {
  int lane = threadIdx.x & 63;
  int wid = blockIdx.x * (blockDim.x >> 6) + (threadIdx.x >> 6);
  int wstride = gridDim.x * (blockDim.x >> 6);
  int cq = lane & 15;
  float2 attq = ((const float2*)att)[lane];
  float2 b2q = ((const float2*)b2)[cq];
  float2 gq = ((const float2*)g)[cq];
  float2 beq = ((const float2*)be)[cq];
  for (int i = wid; i < N; i += wstride) {
    float2 xrq = ((const float2*)xr2)[i * 64 + lane];
    float a0 = 0.f, a1 = 0.f, m = -INFINITY, den = 0.f;
    int beg = offs[i], end = offs[i + 1];
    for (int p = beg; p < end; ++p) {
      int s = esrc[p];
      float2 xl = ((const float2*)xl2)[s * 64 + lane];
      float t0 = xl.x + xrq.x; t0 = t0 > 0.f ? t0 : NEG_SLOPE * t0;
      float t1 = xl.y + xrq.y; t1 = t1 > 0.f ? t1 : NEG_SLOPE * t1;
      float sc = fmaf(attq.y, t1, attq.x * t0);
#pragma unroll
      for (int msk = 8; msk >= 1; msk >>= 1) sc += __shfl_xor(sc, msk, 64);
      float mn = fmaxf(m, sc), corr = __expf(m - mn), w = __expf(sc - mn);
      den = fmaf(den, corr, w);
      a0 = fmaf(a0, corr, w * xl.x);
      a1 = fmaf(a1, corr, w * xl.y);
      m = mn;
    }
    float inv = 1.0f / den;
    float v0 = a0 * inv, v1 = a1 * inv;
    v0 += __shfl_xor(v0, 16, 64); v0 += __shfl_xor(v0, 32, 64);
    v1 += __shfl_xor(v1, 16, 64); v1 += __shfl_xor(v1, 32, 64);
    v0 = 0.25f * v0 + b2q.x;
    v1 = 0.25f * v1 + b2q.y;
    float s1 = v0 + v1;
#pragma unroll
    for (int msk = 8; msk >= 1; msk >>= 1) s1 += __shfl_xor(s1, msk, 64);
    float mu = s1 * (1.0f / 32.0f);
    float d0 = v0 - mu, d1 = v1 - mu;
    float s2 = d0 * d0 + d1 * d1;
#pragma unroll
    for (int msk = 8; msk >= 1; msk >>= 1) s2 += __shfl_xor(s2, msk, 64);
    float rstd = rsqrtf(s2 * (1.0f / 32.0f) + LN_EPS);
    float y0 = fmaxf(fmaf(d0 * rstd, gq.x, beq.x), 0.f);
    float y1 = fmaxf(fmaf(d1 * rstd, gq.y, beq.y), 0.f);
    if (lane < 16) ((float2*)h2)[i * 16 + cq] = make_float2(y0, y1);
  }
}

// ---------------- global mean pool ----------------
__global__ void pool_kernel(const float* __restrict__ h2, const int* __restrict__ batch,
                            float* __restrict__ pooled, int* __restrict__ cntG, int N) {
  int idx = blockIdx.x * blockDim.x + threadIdx.x;
  if (idx >= N * 32) return;
  int n = idx >> 5, c = idx & 31;
  int gidx = batch[n];
  atomicAdd(&pooled[gidx * 32 + c], h2[idx]);
  if (c == 0) atomicAdd(&cntG[gidx], 1);
}

__global__ void final_kernel(const float* __restrict__ pooled, const int* __restrict__ cntG,
                             float* __restrict__ out, int M) {
  int idx = blockIdx.x * blockDim.x + threadIdx.x;
  if (idx >= M) return;
  int gidx = idx >> 5;
  int c = cntG[gidx];
  float cf = (float)(c > 0 ? c : 1);
  out[idx] = pooled[idx] / cf;
}

extern "C" void kernel_launch(void* const* d_in, const int* in_sizes, int n_in,
                              void* d_out, int out_size, void* d_ws, size_t ws_size,
                              hipStream_t stream) {
  const float* x    = (const float*)d_in[0];
  const int*   ei   = (const int*)d_in[1];
  const int*   batch= (const int*)d_in[2];
  const float* Wl1  = (const float*)d_in[3];
  const float* bl1  = (const float*)d_in[4];
  const float* Wr1  = (const float*)d_in[5];
  const float* br1  = (const float*)d_in[6];
  const float* att1 = (const float*)d_in[7];
  const float* b1   = (const float*)d_in[8];
  const float* ln1g = (const float*)d_in[9];
  const float* ln1b = (const float*)d_in[10];
  const float* Wl2  = (const float*)d_in[11];
  const float* bl2  = (const float*)d_in[12];
  const float* Wr2  = (const float*)d_in[13];
  const float* br2  = (const float*)d_in[14];
  const float* att2 = (const float*)d_in[15];
  const float* b2   = (const float*)d_in[16];
  const float* ln2g = (const float*)d_in[17];
  const float* ln2b = (const float*)d_in[18];

  int N = in_sizes[0] / 8;
  int E = in_sizes[1] / 2;
  int G = out_size / 32;

  char* ws = (char*)d_ws;
  size_t off = 0;
  auto alloc = [&](size_t bytes) -> void* {
    void* p = (void*)(ws + off);
    off += (bytes + 255) & ~(size_t)255;
    return p;
  };
  int*   cnt    = (int*)alloc((size_t)N * 4);
  int*   offs   = (int*)alloc((size_t)(N + 1) * 4);
  int*   cursor = (int*)alloc((size_t)N * 4);
  int*   esrc   = (int*)alloc((size_t)(E + N) * 4);
  float* xl1    = (float*)alloc((size_t)N * 256 * 4);
  float* xr1    = (float*)alloc((size_t)N * 256 * 4);
  float* h1     = (float*)alloc((size_t)N * 64 * 4);
  float* xl2    = (float*)alloc((size_t)N * 128 * 4);
  float* xr2    = (float*)alloc((size_t)N * 128 * 4);
  float* h2     = (float*)alloc((size_t)N * 32 * 4);
  float* pooled = (float*)alloc((size_t)G * 32 * 4);
  int*   cntG   = (int*)alloc((size_t)G * 4);

  hipMemsetAsync(cnt, 0, (size_t)N * 4, stream);
  hipMemsetAsync(cursor, 0, (size_t)N * 4, stream);
  hipMemsetAsync(pooled, 0, (size_t)G * 32 * 4, stream);
  hipMemsetAsync(cntG, 0, (size_t)G * 4, stream);

  int tot = E + N;
  hist_kernel<<<(tot + 255) / 256, 256, 0, stream>>>(ei, E, N, cnt);
  scan_kernel<<<1, 1024, 0, stream>>>(cnt, offs, N);
  scatter_kernel<<<(tot + 255) / 256, 256, 0, stream>>>(ei, E, N, offs, cursor, esrc);

  gemm1_kernel<<<1024, 256, 0, stream>>>(x, Wl1, bl1, Wr1, br1, xl1, xr1, N);
  attn1_kernel<<<2048, 256, 0, stream>>>(xl1, xr1, att1, b1, ln1g, ln1b, offs, esrc, h1, N);
  gemm2_kernel<<<2048, 128, 0, stream>>>(h1, Wl2, bl2, Wr2, br2, xl2, xr2, N);
  attn2_kernel<<<2048, 256, 0, stream>>>(xl2, xr2, att2, b2, ln2g, ln2b, offs, esrc, h2, N);

  pool_kernel<<<(N * 32 + 255) / 256, 256, 0, stream>>>(h2, batch, pooled, cntG, N);
  final_kernel<<<(out_size + 255) / 256, 256, 0, stream>>>(pooled, cntG, (float*)d_out, out_size);
}